// Round 7
// baseline (355.511 us; speedup 1.0000x reference)
//
#include <hip/hip_runtime.h>

#define B_SZ  1024
#define NSEQ  512
#define D_INP 30
#define H     64
#define MB    4
#define L2E   1.4426950408889634f
// shorts per batch-plane of staged x: 512 timesteps x 32 (30 + 2 pad) + 16
// dwords of stagger so consecutive planes start 16 banks apart (2-way max).
#define XPLANE (NSEQ * 32 + 32)

typedef short s16x8 __attribute__((ext_vector_type(8)));
typedef float f32x4 __attribute__((ext_vector_type(4)));

#if __has_builtin(__builtin_amdgcn_exp2f)
#define EXP2(x) __builtin_amdgcn_exp2f(x)
#else
#define EXP2(x) exp2f(x)
#endif

__device__ __forceinline__ float rcp_f(float v) { return __builtin_amdgcn_rcpf(v); }

__device__ __forceinline__ f32x4 mfma16(s16x8 a, s16x8 b, f32x4 c) {
  return __builtin_amdgcn_mfma_f32_16x16x32_bf16(a, b, c, 0, 0, 0);
}

__device__ __forceinline__ short bf16_rne(float f) {
  unsigned u = __float_as_uint(f);
  unsigned r = (u + 0x7FFFu + ((u >> 16) & 1u)) >> 16;
  return (short)r;
}

__device__ __forceinline__ s16x8 rne8(const float* f) {
  s16x8 o;
#pragma unroll
  for (int i = 0; i < 8; ++i) o[i] = bf16_rne(f[i]);
  return o;
}

__device__ __forceinline__ void split8(const float* f, s16x8& hi, s16x8& lo) {
#pragma unroll
  for (int i = 0; i < 8; ++i) {
    unsigned ub = __float_as_uint(f[i]);
    hi[i] = (short)(ub >> 16);
    float hf = __uint_as_float(ub & 0xFFFF0000u);
    float lf = f[i] - hf;
    lo[i] = (short)(__float_as_uint(lf) >> 16);
  }
}

// lgkmcnt-only barrier (no global ops in the loop at all now).
__device__ __forceinline__ void wg_barrier() {
  asm volatile("s_waitcnt lgkmcnt(0)" ::: "memory");
  __builtin_amdgcn_s_barrier();
  asm volatile("" ::: "memory");
}

// ---------------------------------------------------------------------------
// Kernel A: fold FC into the input-side gate GEMM (fp32).
// Parallelized over 8 blocks (32 rows each) — was 1 block on 1 CU.
// ---------------------------------------------------------------------------
__global__ __launch_bounds__(256) void prep_kernel(
    const float* __restrict__ W_fc, const float* __restrict__ b_fc,
    const float* __restrict__ W_ih, const float* __restrict__ b_ih,
    const float* __restrict__ b_hh,
    float* __restrict__ wsW, float* __restrict__ wsB) {
  __shared__ float fc[H * D_INP];
  __shared__ float bfc[H];
  const int u = threadIdx.x;
  for (int i = u; i < H * D_INP; i += 256) fc[i] = W_fc[i];
  if (u < H) bfc[u] = b_fc[u];
  __syncthreads();

  const int n = blockIdx.x * 32 + u;   // this block's 32 rows
  if (u < 32) {
    float wih[H];
#pragma unroll
    for (int i = 0; i < H; ++i) wih[i] = W_ih[n * H + i];

    for (int k = 0; k < D_INP; ++k) {
      float s = 0.f;
#pragma unroll
      for (int i = 0; i < H; ++i) s = fmaf(wih[i], fc[i * D_INP + k], s);
      wsW[n * 32 + k] = s;
    }
    wsW[n * 32 + 30] = 0.f;
    wsW[n * 32 + 31] = 0.f;

    float bb = b_ih[n] + b_hh[n];
#pragma unroll
    for (int i = 0; i < H; ++i) bb = fmaf(wih[i], bfc[i], bb);
    wsB[n] = bb;
  }
}

// ---------------------------------------------------------------------------
// Kernel B: MFMA LSTM, 256 blocks x 256 threads (4 waves, 1 blk/CU).
// Round-4 math, S-waves deleted: the block's ENTIRE x slice (4 batches x 512
// steps x 30) is pre-converted to bf16 and staged in LDS once in the
// prologue (123 KB), so the loop has zero global traffic and zero staging
// work. All 4 waves are G waves (wave w owns units [16w,16w+16), all 4
// gates); the rotating h->logit (wave t&3) reuses that wave's already-loaded
// h-frags and queues behind the gate MFMAs (off the acc dependency).
// Barrier spans 4 waves instead of 8. Batch b sits at MFMA row 4b (uniform
// r=0 activation). Lanes with low%4!=0 read a valid broadcast x address
// (low>>2) and feed dead A-rows -> dead D-rows (never read).
// Numerics bit-identical to round 4 -> absmax must stay 1.525879e-05.
// ---------------------------------------------------------------------------
__global__ __launch_bounds__(256, 1) void lstm_mfma(
    const float* __restrict__ x, const float* __restrict__ W_hh,
    const float* __restrict__ wsW, const float* __restrict__ wsB,
    const float* __restrict__ W_last, float* __restrict__ out) {

  __shared__ __align__(16) short xfull[4 * XPLANE];  // 131.3 KB
  __shared__ __align__(16) short hpl[2][16][72];     // 4.6 KB
  __shared__ __align__(16) float logitsT[NSEQ + 1][MB]; // 8.2 KB

  const int u   = threadIdx.x;    // 0..255
  const int w   = u >> 6;         // wave 0..3
  const int l   = u & 63;
  const int low = l & 15;
  const int q   = l >> 4;
  const int b0  = blockIdx.x * MB;
  const int cw  = w;              // unit col-block 0..3

  // ---- B-frags for all 4 gates of col-block cw ----
  // gate order: 0=i, 1=f, 2=g, 3=o ; unit n = 64*g + 16*cw + low.
  s16x8 whh[4][2], wcb[4];
  float xb[4];
  s16x8 wl_h[2], wl_l[2];
  {
    float tmp[8];
#pragma unroll
    for (int g2 = 0; g2 < 4; ++g2) {
      const int n = 64 * g2 + 16 * cw + low;
      const float sc = (g2 == 2) ? (2.0f * L2E) : L2E;
#pragma unroll
      for (int kt = 0; kt < 2; ++kt) {
        const float* p = W_hh + n * H + kt * 32 + q * 8;
#pragma unroll
        for (int j = 0; j < 8; ++j) tmp[j] = p[j] * sc;
        whh[g2][kt] = rne8(tmp);
      }
      const float* pw = wsW + n * 32 + q * 8;
#pragma unroll
      for (int j = 0; j < 8; ++j) tmp[j] = pw[j] * sc;
      wcb[g2] = rne8(tmp);
      xb[g2] = wsB[n] * sc;
    }
#pragma unroll
    for (int kt = 0; kt < 2; ++kt) {
#pragma unroll
      for (int j = 0; j < 8; ++j)
        tmp[j] = (low == 0) ? W_last[kt * 32 + q * 8 + j] : 0.0f;
      split8(tmp, wl_h[kt], wl_l[kt]);
    }
  }

  // ---- zero x plane (pads must be 0) + h planes ----
  for (int i = u; i < 4 * XPLANE / 2; i += 256) ((int*)xfull)[i] = 0;
  for (int i = u; i < 2 * 16 * 72 / 2; i += 256) ((int*)hpl)[i] = 0;
  __syncthreads();

  // ---- stage the block's whole x slice as bf16 (once) ----
  // xfull[b][t*32 + k] = bf16(x[b0+b][t][k]), k<30; k=30,31 stay 0.
#pragma unroll 1
  for (int b = 0; b < MB; ++b) {
    const float* xb_ptr = x + (size_t)(b0 + b) * NSEQ * D_INP;
    for (int j = u; j < NSEQ * 15; j += 256) {
      const int t = j / 15, kk = j - t * 15;
      float2 v = *(const float2*)(xb_ptr + t * D_INP + kk * 2);
      short2 s2;
      s2.x = bf16_rne(v.x);
      s2.y = bf16_rne(v.y);
      *(short2*)&xfull[b * XPLANE + t * 32 + kk * 2] = s2;
    }
  }
  __syncthreads();

  // x A-frag for step t: 4-lane broadcast per (batch=low>>2, q) group.
  auto xfrag = [&](int t) -> s16x8 {
    return *(const s16x8*)&xfull[(low >> 2) * XPLANE + t * 32 + q * 8];
  };

  // xacc prefetch for t = 0
  f32x4 xacc[4];
  {
    s16x8 xah = xfrag(0);
#pragma unroll
    for (int g2 = 0; g2 < 4; ++g2) {
      f32x4 a = {xb[g2], xb[g2], xb[g2], xb[g2]};
      xacc[g2] = mfma16(xah, wcb[g2], a);
    }
  }

  float cst = 0.f;   // cell state (batch q, unit 16cw+low)

  for (int t = 0; t < NSEQ; ++t) {
    // ---- recurrence critical path ----
    const short* hp = &hpl[(t + 1) & 1][low][0];
    s16x8 ah0 = *(const s16x8*)(hp + q * 8);
    s16x8 ah1 = *(const s16x8*)(hp + 32 + q * 8);

    f32x4 acc[4];
#pragma unroll
    for (int g2 = 0; g2 < 4; ++g2) acc[g2] = mfma16(ah0, whh[g2][0], xacc[g2]);
#pragma unroll
    for (int g2 = 0; g2 < 4; ++g2) acc[g2] = mfma16(ah1, whh[g2][1], acc[g2]);

    // prefetch next timestep's x-side acc (independent of h)
    if (t + 1 < NSEQ) {
      s16x8 xah = xfrag(t + 1);
#pragma unroll
      for (int g2 = 0; g2 < 4; ++g2) {
        f32x4 a = {xb[g2], xb[g2], xb[g2], xb[g2]};
        xacc[g2] = mfma16(xah, wcb[g2], a);
      }
    }

    // rotating logit of h_{t-1}: reuses this wave's h-frags, queues after
    // the gate/xacc MFMAs (doesn't extend the acc dependency).
    if (w == (t & 3)) {
      f32x4 aL = {0.f, 0.f, 0.f, 0.f};
      aL = mfma16(ah0, wl_h[0], aL);
      aL = mfma16(ah1, wl_h[1], aL);
      f32x4 bL = {0.f, 0.f, 0.f, 0.f};
      bL = mfma16(ah0, wl_l[0], bL);
      bL = mfma16(ah1, wl_l[1], bL);
      aL = aL + bL;
      if (low == 0) logitsT[t][q] = aL[0];   // batch q at D row 4q, col 0
    }

    // ---- activation: single live row r=0 (batch q) ----
    float gi = rcp_f(1.0f + EXP2(-acc[0][0]));
    float gf = rcp_f(1.0f + EXP2(-acc[1][0]));
    float gg = 1.0f - 2.0f * rcp_f(1.0f + EXP2(acc[2][0]));
    float go = rcp_f(1.0f + EXP2(-acc[3][0]));
    float cc = fmaf(gf, cst, gi * gg);
    cst = cc;
    float h = go * (1.0f - 2.0f * rcp_f(1.0f + EXP2(cc * (2.0f * L2E))));
    hpl[t & 1][q * 4][16 * cw + low] = bf16_rne(h);

    wg_barrier();
  }

  // final logit from h_511 (in plane 1)
  if (w == 0) {
    const short* hp = &hpl[1][low][0];
    s16x8 ah0 = *(const s16x8*)(hp + q * 8);
    s16x8 ah1 = *(const s16x8*)(hp + 32 + q * 8);
    f32x4 aL = {0.f, 0.f, 0.f, 0.f};
    aL = mfma16(ah0, wl_h[0], aL);
    aL = mfma16(ah1, wl_h[1], aL);
    f32x4 bL = {0.f, 0.f, 0.f, 0.f};
    bL = mfma16(ah0, wl_l[0], bL);
    bL = mfma16(ah1, wl_l[1], bL);
    aL = aL + bL;
    if (low == 0) logitsT[NSEQ][q] = aL[0];
  }
  __syncthreads();

  // ---- softmax over time (first 64 threads; 4 batches x 16 lanes) ----
  if (u < 16 * MB) {
    const int m = u >> 4, li = u & 15;
    float lv[32];
    float mx = -3.0e38f;
#pragma unroll
    for (int s = 0; s < 32; ++s) {
      lv[s] = logitsT[1 + li + 16 * s][m];
      mx = fmaxf(mx, lv[s]);
    }
#pragma unroll
    for (int d = 1; d < 16; d <<= 1) mx = fmaxf(mx, __shfl_xor(mx, d, 16));
    float sum = 0.f;
#pragma unroll
    for (int s = 0; s < 32; ++s) { lv[s] = __expf(lv[s] - mx); sum += lv[s]; }
#pragma unroll
    for (int d = 1; d < 16; d <<= 1) sum += __shfl_xor(sum, d, 16);
    float inv = 1.0f / sum;
#pragma unroll
    for (int s = 0; s < 32; ++s)
      out[(size_t)(b0 + m) * NSEQ + li + 16 * s] = lv[s] * inv;
  }
}

// ---------------------------------------------------------------------------
extern "C" void kernel_launch(void* const* d_in, const int* in_sizes, int n_in,
                              void* d_out, int out_size, void* d_ws, size_t ws_size,
                              hipStream_t stream) {
  const float* x      = (const float*)d_in[0];
  const float* W_fc   = (const float*)d_in[1];
  const float* b_fc   = (const float*)d_in[2];
  const float* W_ih   = (const float*)d_in[3];
  const float* W_hh   = (const float*)d_in[4];
  const float* b_ih   = (const float*)d_in[5];
  const float* b_hh   = (const float*)d_in[6];
  const float* W_last = (const float*)d_in[7];
  // d_in[8] = b_last: cancels in softmax.

  float* out = (float*)d_out;
  float* wsW = (float*)d_ws;          // 256*32 floats
  float* wsB = wsW + 256 * 32;        // 256 floats

  prep_kernel<<<8, 256, 0, stream>>>(W_fc, b_fc, W_ih, b_ih, b_hh, wsW, wsB);
  lstm_mfma<<<B_SZ / MB, 256, 0, stream>>>(x, W_hh, wsW, wsB, W_last, out);
}

// Round 8
// 319.419 us; speedup vs baseline: 1.1130x; 1.1130x over previous
//
#include <hip/hip_runtime.h>

#define B_SZ  1024
#define NSEQ  512
#define D_INP 30
#define H     64
#define MB    8           // two groups of 4 batches per block
#define NG    2
#define TCH   8
#define L2E   1.4426950408889634f

typedef short s16x8 __attribute__((ext_vector_type(8)));
typedef float f32x4 __attribute__((ext_vector_type(4)));

#if __has_builtin(__builtin_amdgcn_exp2f)
#define EXP2(x) __builtin_amdgcn_exp2f(x)
#else
#define EXP2(x) exp2f(x)
#endif

__device__ __forceinline__ float rcp_f(float v) { return __builtin_amdgcn_rcpf(v); }

__device__ __forceinline__ f32x4 mfma16(s16x8 a, s16x8 b, f32x4 c) {
  return __builtin_amdgcn_mfma_f32_16x16x32_bf16(a, b, c, 0, 0, 0);
}

__device__ __forceinline__ short bf16_rne(float f) {
  unsigned u = __float_as_uint(f);
  unsigned r = (u + 0x7FFFu + ((u >> 16) & 1u)) >> 16;
  return (short)r;
}

__device__ __forceinline__ s16x8 rne8(const float* f) {
  s16x8 o;
#pragma unroll
  for (int i = 0; i < 8; ++i) o[i] = bf16_rne(f[i]);
  return o;
}

__device__ __forceinline__ void split8(const float* f, s16x8& hi, s16x8& lo) {
#pragma unroll
  for (int i = 0; i < 8; ++i) {
    unsigned ub = __float_as_uint(f[i]);
    hi[i] = (short)(ub >> 16);
    float hf = __uint_as_float(ub & 0xFFFF0000u);
    float lf = f[i] - hf;
    lo[i] = (short)(__float_as_uint(lf) >> 16);
  }
}

// lgkmcnt-only barrier: LDS ordering preserved, global loads stay in flight.
__device__ __forceinline__ void wg_barrier() {
  asm volatile("s_waitcnt lgkmcnt(0)" ::: "memory");
  __builtin_amdgcn_s_barrier();
  asm volatile("" ::: "memory");
}

// ---------------------------------------------------------------------------
// Kernel A: fold FC into the input-side gate GEMM (fp32). 8 blocks.
// ---------------------------------------------------------------------------
__global__ __launch_bounds__(256) void prep_kernel(
    const float* __restrict__ W_fc, const float* __restrict__ b_fc,
    const float* __restrict__ W_ih, const float* __restrict__ b_ih,
    const float* __restrict__ b_hh,
    float* __restrict__ wsW, float* __restrict__ wsB) {
  __shared__ float fc[H * D_INP];
  __shared__ float bfc[H];
  const int u = threadIdx.x;
  for (int i = u; i < H * D_INP; i += 256) fc[i] = W_fc[i];
  if (u < H) bfc[u] = b_fc[u];
  __syncthreads();

  const int n = blockIdx.x * 32 + u;
  if (u < 32) {
    float wih[H];
#pragma unroll
    for (int i = 0; i < H; ++i) wih[i] = W_ih[n * H + i];

    for (int k = 0; k < D_INP; ++k) {
      float s = 0.f;
#pragma unroll
      for (int i = 0; i < H; ++i) s = fmaf(wih[i], fc[i * D_INP + k], s);
      wsW[n * 32 + k] = s;
    }
    wsW[n * 32 + 30] = 0.f;
    wsW[n * 32 + 31] = 0.f;

    float bb = b_ih[n] + b_hh[n];
#pragma unroll
    for (int i = 0; i < H; ++i) bb = fmaf(wih[i], bfc[i], bb);
    wsB[n] = bb;
  }
}

// ---------------------------------------------------------------------------
// Kernel B: MFMA LSTM, 128 blocks x 512 threads (8 waves, 2/SIMD).
// TWO independent recurrences (groups A,B = batches 0-3 / 4-7 of the block)
// advance per barrier interval on the same G waves: A's latency chain is
// filled by B's independent MFMAs/activations and vice versa, and the
// barrier cost amortizes over 2 logical steps. Weights are shared; only
// state (xacc, cell, h-planes) duplicates. Wall time = 512 x per-step
// critical path (CU count irrelevant; r7 proved 1 wave/SIMD exposes the
// chain, r4 proved the G/S split works).
// Group math identical to round 4: batch b at MFMA row 4b (uniform r=0
// activation); G wave cw owns units [16cw,16cw+16), all 4 gates; x-side
// MFMAs prefetched one step ahead. S waves: x staging (slots 2k,2k+1) +
// per-group logit every step (waves 4,5). One lgkmcnt-only barrier per
// interval; vmcnt never drained in-loop.
// xa holds batches packed at rows 0-7 (row = global batch); group g's
// A-frag lane (q,low) reads LDS row 4g+(low>>2) (A-row stays low=4b).
// absmax must stay exactly 1.525879e-05.
// ---------------------------------------------------------------------------
__global__ __launch_bounds__(512, 2) void lstm_mfma(
    const float* __restrict__ x, const float* __restrict__ W_hh,
    const float* __restrict__ wsW, const float* __restrict__ wsB,
    const float* __restrict__ W_last, float* __restrict__ out) {

  __shared__ short xa[2][TCH][64][8];              // 16 KB
  __shared__ short hpl[NG][2][16][72];             // 9.2 KB
  __shared__ float logitsT[NSEQ + 1][MB];          // 16.4 KB

  const int u   = threadIdx.x;    // 0..511
  const int w   = u >> 6;         // wave 0..7
  const int l   = u & 63;
  const int low = l & 15;
  const int q   = l >> 4;
  const int b0  = blockIdx.x * MB;
  const bool isS = (w >= 4);
  const int cw  = w & 3;          // G: unit col-block / S: service id

  // ---- G waves: B-frags for all 4 gates of col-block cw (shared by A,B) ----
  s16x8 whh[4][2], wcb[4];
  float xb[4];
  s16x8 wl_h[2], wl_l[2];

  if (!isS) {
    float tmp[8];
#pragma unroll
    for (int g2 = 0; g2 < 4; ++g2) {
      const int n = 64 * g2 + 16 * cw + low;
      const float sc = (g2 == 2) ? (2.0f * L2E) : L2E;
#pragma unroll
      for (int kt = 0; kt < 2; ++kt) {
        const float* p = W_hh + n * H + kt * 32 + q * 8;
#pragma unroll
        for (int j = 0; j < 8; ++j) tmp[j] = p[j] * sc;
        whh[g2][kt] = rne8(tmp);
      }
      const float* pw = wsW + n * 32 + q * 8;
#pragma unroll
      for (int j = 0; j < 8; ++j) tmp[j] = pw[j] * sc;
      wcb[g2] = rne8(tmp);
      xb[g2] = wsB[n] * sc;
    }
  } else {
#pragma unroll
    for (int kt = 0; kt < 2; ++kt) {
      float tmp[8];
#pragma unroll
      for (int j = 0; j < 8; ++j)
        tmp[j] = (low == 0) ? W_last[kt * 32 + q * 8 + j] : 0.0f;
      split8(tmp, wl_h[kt], wl_l[kt]);
    }
  }

  // zero h planes (dead rows must stay zero)
  for (int i = u; i < NG * 2 * 16 * 72 / 2; i += 512) ((int*)hpl)[i] = 0;

  // ---- S-wave x staging: wave cw handles chunk-slots 2cw, 2cw+1 ----
  // xa row = global batch (0..7 live); rows 8-15 never read.
  const int srow = l & 15, sq = l >> 4;
  const bool sact = (srow < MB);
  const float* xrow = x + (size_t)(b0 + (srow & (MB - 1))) * NSEQ * D_INP + sq * 8;
  float pf0[8], pf1[8];
  auto ld8 = [&](const float* p, float* pf) {
    float2 v0 = *(const float2*)(p);
    float2 v1 = *(const float2*)(p + 2);
    float2 v2 = *(const float2*)(p + 4);
    float2 v3 = (sq < 3) ? *(const float2*)(p + 6) : make_float2(0.f, 0.f);
    pf[0] = v0.x; pf[1] = v0.y; pf[2] = v1.x; pf[3] = v1.y;
    pf[4] = v2.x; pf[5] = v2.y; pf[6] = v3.x; pf[7] = v3.y;
  };
  auto stage_load = [&](int t0) {
    const float* p = xrow + (size_t)(t0 + 2 * cw) * D_INP;
    ld8(p, pf0);
    ld8(p + D_INP, pf1);
  };
  auto stage_write = [&](int buf) {
    if (sact) {
      *(s16x8*)&xa[buf][2 * cw][l][0] = rne8(pf0);
      *(s16x8*)&xa[buf][2 * cw + 1][l][0] = rne8(pf1);
    }
  };

  if (isS) { stage_load(0); stage_write(0); }
  __syncthreads();

  // group g's x A-frag for step t (LDS row 4g + (low>>2), A-row stays low)
  auto xfrag = [&](int g, int t) -> s16x8 {
    return *(const s16x8*)&xa[(t >> 3) & 1][t & 7][(q << 4) | (4 * g + (low >> 2))][0];
  };

  // xacc prefetch for t = 0, both groups
  f32x4 xaccA[4], xaccB[4];
  if (!isS) {
    s16x8 xA = xfrag(0, 0), xB = xfrag(1, 0);
#pragma unroll
    for (int g2 = 0; g2 < 4; ++g2) {
      f32x4 a = {xb[g2], xb[g2], xb[g2], xb[g2]};
      xaccA[g2] = mfma16(xA, wcb[g2], a);
      xaccB[g2] = mfma16(xB, wcb[g2], a);
    }
  }

  float cstA = 0.f, cstB = 0.f;   // cell state (batch q, unit 16cw+low)

#define ACT_H(ACC0, ACC1, ACC2, ACC3, CST, GRP)                              \
  {                                                                          \
    float gi = rcp_f(1.0f + EXP2(-(ACC0)));                                  \
    float gf = rcp_f(1.0f + EXP2(-(ACC1)));                                  \
    float gg = 1.0f - 2.0f * rcp_f(1.0f + EXP2((ACC2)));                     \
    float go = rcp_f(1.0f + EXP2(-(ACC3)));                                  \
    float cc = fmaf(gf, CST, gi * gg);                                       \
    CST = cc;                                                                \
    float hh2 = go * (1.0f - 2.0f * rcp_f(1.0f + EXP2(cc * (2.0f * L2E)))); \
    hpl[GRP][t & 1][q * 4][16 * cw + low] = bf16_rne(hh2);                   \
  }

  for (int t = 0; t < NSEQ; ++t) {
    const int tt = t & (TCH - 1);
    const int cb = (t >> 3) & 1;
    if (!isS) {
      // ---- both groups' h frags issue right after the barrier ----
      const short* hpA = &hpl[0][(t + 1) & 1][low][0];
      const short* hpB = &hpl[1][(t + 1) & 1][low][0];
      s16x8 a0A = *(const s16x8*)(hpA + q * 8);
      s16x8 a1A = *(const s16x8*)(hpA + 32 + q * 8);
      s16x8 a0B = *(const s16x8*)(hpB + q * 8);
      s16x8 a1B = *(const s16x8*)(hpB + 32 + q * 8);

      f32x4 accA[4], accB[4];
#pragma unroll
      for (int g2 = 0; g2 < 4; ++g2) accA[g2] = mfma16(a0A, whh[g2][0], xaccA[g2]);
#pragma unroll
      for (int g2 = 0; g2 < 4; ++g2) accA[g2] = mfma16(a1A, whh[g2][1], accA[g2]);
#pragma unroll
      for (int g2 = 0; g2 < 4; ++g2) accB[g2] = mfma16(a0B, whh[g2][0], xaccB[g2]);
#pragma unroll
      for (int g2 = 0; g2 < 4; ++g2) accB[g2] = mfma16(a1B, whh[g2][1], accB[g2]);

      // prefetch next step's x-side acc for both groups (independent of h)
      if (t + 1 < NSEQ) {
        s16x8 xA = xfrag(0, t + 1), xB = xfrag(1, t + 1);
#pragma unroll
        for (int g2 = 0; g2 < 4; ++g2) {
          f32x4 a = {xb[g2], xb[g2], xb[g2], xb[g2]};
          xaccA[g2] = mfma16(xA, wcb[g2], a);
          xaccB[g2] = mfma16(xB, wcb[g2], a);
        }
      }

      // ---- activations: two independent chains (compiler interleaves) ----
      ACT_H(accA[0][0], accA[1][0], accA[2][0], accA[3][0], cstA, 0);
      ACT_H(accB[0][0], accB[1][0], accB[2][0], accB[3][0], cstB, 1);
    } else {
      // ---- service waves ----
      if (cw < NG) {
        // logit of group cw's h_{t-1}, every step
        const short* hp = &hpl[cw][(t + 1) & 1][low][0];
        s16x8 ah0 = *(const s16x8*)(hp + q * 8);
        s16x8 ah1 = *(const s16x8*)(hp + 32 + q * 8);
        f32x4 aL = {0.f, 0.f, 0.f, 0.f};
        aL = mfma16(ah0, wl_h[0], aL);
        aL = mfma16(ah1, wl_h[1], aL);
        f32x4 bL = {0.f, 0.f, 0.f, 0.f};
        bL = mfma16(ah0, wl_l[0], bL);
        bL = mfma16(ah1, wl_l[1], bL);
        aL = aL + bL;
        if (low == 0) logitsT[t][4 * cw + q] = aL[0];
      }
      if (tt == 0 && t + TCH < NSEQ) stage_load(t + TCH);
      if (tt == 4 && t + 4 < NSEQ) stage_write(cb ^ 1);
    }
    wg_barrier();
  }
#undef ACT_H

  // final logits from h_511 (plane 1), one S wave per group
  if (w == 4 || w == 5) {
    const int g = w - 4;
    const short* hp = &hpl[g][1][low][0];
    s16x8 ah0 = *(const s16x8*)(hp + q * 8);
    s16x8 ah1 = *(const s16x8*)(hp + 32 + q * 8);
    f32x4 aL = {0.f, 0.f, 0.f, 0.f};
    aL = mfma16(ah0, wl_h[0], aL);
    aL = mfma16(ah1, wl_h[1], aL);
    f32x4 bL = {0.f, 0.f, 0.f, 0.f};
    bL = mfma16(ah0, wl_l[0], bL);
    bL = mfma16(ah1, wl_l[1], bL);
    aL = aL + bL;
    if (low == 0) logitsT[NSEQ][4 * g + q] = aL[0];
  }
  __syncthreads();

  // ---- softmax over time (first 16*MB = 128 threads) ----
  if (u < 16 * MB) {
    const int m = u >> 4, li = u & 15;
    float lv[32];
    float mx = -3.0e38f;
#pragma unroll
    for (int s = 0; s < 32; ++s) {
      lv[s] = logitsT[1 + li + 16 * s][m];
      mx = fmaxf(mx, lv[s]);
    }
#pragma unroll
    for (int d = 1; d < 16; d <<= 1) mx = fmaxf(mx, __shfl_xor(mx, d, 16));
    float sum = 0.f;
#pragma unroll
    for (int s = 0; s < 32; ++s) { lv[s] = __expf(lv[s] - mx); sum += lv[s]; }
#pragma unroll
    for (int d = 1; d < 16; d <<= 1) sum += __shfl_xor(sum, d, 16);
    float inv = 1.0f / sum;
#pragma unroll
    for (int s = 0; s < 32; ++s)
      out[(size_t)(b0 + m) * NSEQ + li + 16 * s] = lv[s] * inv;
  }
}

// ---------------------------------------------------------------------------
extern "C" void kernel_launch(void* const* d_in, const int* in_sizes, int n_in,
                              void* d_out, int out_size, void* d_ws, size_t ws_size,
                              hipStream_t stream) {
  const float* x      = (const float*)d_in[0];
  const float* W_fc   = (const float*)d_in[1];
  const float* b_fc   = (const float*)d_in[2];
  const float* W_ih   = (const float*)d_in[3];
  const float* W_hh   = (const float*)d_in[4];
  const float* b_ih   = (const float*)d_in[5];
  const float* b_hh   = (const float*)d_in[6];
  const float* W_last = (const float*)d_in[7];
  // d_in[8] = b_last: cancels in softmax.

  float* out = (float*)d_out;
  float* wsW = (float*)d_ws;          // 256*32 floats
  float* wsB = wsW + 256 * 32;        // 256 floats

  prep_kernel<<<8, 256, 0, stream>>>(W_fc, b_fc, W_ih, b_ih, b_hh, wsW, wsB);
  lstm_mfma<<<B_SZ / MB, 512, 0, stream>>>(x, W_hh, wsW, wsB, W_last, out);
}